// Round 1
// baseline (904.600 us; speedup 1.0000x reference)
//
#include <hip/hip_runtime.h>
#include <math.h>

#define N_NODES 10000
#define N_EDGES 160000
#define SEQ 16
#define F_INC 4
#define HID 64
#define HID2 128

// ---------------- graph preprocessing ----------------

__global__ __launch_bounds__(256) void hist_kernel(const int* __restrict__ dst,
                                                   int* __restrict__ counts) {
  int e = blockIdx.x * 256 + threadIdx.x;
  if (e < N_EDGES) atomicAdd(&counts[dst[e]], 1);
}

__global__ __launch_bounds__(256) void scan_kernel(const int* __restrict__ counts,
                                                   int* __restrict__ offsets,
                                                   int* __restrict__ cursor,
                                                   float* __restrict__ dinv) {
  __shared__ int partial[256];
  const int CHUNK = 40;  // 256*40 = 10240 >= 10000
  int tid = threadIdx.x;
  int base = tid * CHUNK;
  int s = 0;
  for (int k = 0; k < CHUNK; k++) {
    int idx = base + k;
    if (idx < N_NODES) s += counts[idx];
  }
  partial[tid] = s;
  __syncthreads();
  for (int d = 1; d < 256; d <<= 1) {
    int t = (tid >= d) ? partial[tid - d] : 0;
    __syncthreads();
    partial[tid] += t;
    __syncthreads();
  }
  int run = (tid == 0) ? 0 : partial[tid - 1];
  for (int k = 0; k < CHUNK; k++) {
    int idx = base + k;
    if (idx < N_NODES) {
      offsets[idx] = run;
      cursor[idx] = run;
      dinv[idx] = rsqrtf((float)counts[idx] + 1.0f);
      run += counts[idx];
    }
  }
  if (tid == 255) offsets[N_NODES] = partial[255];
}

__global__ __launch_bounds__(256) void scatter_kernel(const int* __restrict__ src,
                                                      const int* __restrict__ dst,
                                                      const float* __restrict__ dinv,
                                                      int* __restrict__ cursor,
                                                      int* __restrict__ csr_src,
                                                      float* __restrict__ csr_norm) {
  int e = blockIdx.x * 256 + threadIdx.x;
  if (e < N_EDGES) {
    int d = dst[e];
    int s = src[e];
    int pos = atomicAdd(&cursor[d], 1);
    csr_src[pos] = s;
    csr_norm[pos] = dinv[s] * dinv[d];
  }
}

// ---------------- layer kernels ----------------

// x (N,16,4) @ W1 (4,64) -> H (N,16,64), no bias (added post-agg)
__global__ __launch_bounds__(256) void lin1_kernel(const float* __restrict__ X,
                                                   const float* __restrict__ W,
                                                   float* __restrict__ H) {
  int idx = blockIdx.x * 256 + threadIdx.x;  // < 10000*16*64 exactly
  int o = idx & 63;
  int nt = idx >> 6;
  const float* xp = X + (size_t)nt * 4;
  float acc = xp[0] * W[o] + xp[1] * W[64 + o] + xp[2] * W[128 + o] + xp[3] * W[192 + o];
  H[idx] = acc;
}

// GCN aggregation: out[n] = relu( sum_{e:dst=n} h[src_e]*norm_e + h[n]*dinv[n]^2 + bias )
template <int C>
__global__ __launch_bounds__(256) void agg_kernel(const float* __restrict__ h,
                                                  const int* __restrict__ csr_src,
                                                  const float* __restrict__ csr_norm,
                                                  const int* __restrict__ offsets,
                                                  const float* __restrict__ dinv,
                                                  const float* __restrict__ bias,
                                                  float* __restrict__ out) {
  constexpr int ELEMS = SEQ * C;      // 1024 or 2048
  constexpr int V = ELEMS / 1024;     // float4s per thread (1 or 2)
  int n = blockIdx.x, tid = threadIdx.x;
  int beg = offsets[n], end = offsets[n + 1];
  float4 acc[V];
#pragma unroll
  for (int v = 0; v < V; v++) acc[v] = make_float4(0.f, 0.f, 0.f, 0.f);
  for (int e = beg; e < end; ++e) {
    int s = csr_src[e];
    float w = csr_norm[e];
    const float4* hp = (const float4*)(h + (size_t)s * ELEMS);
#pragma unroll
    for (int v = 0; v < V; v++) {
      float4 xv = hp[tid + v * 256];
      acc[v].x += xv.x * w;
      acc[v].y += xv.y * w;
      acc[v].z += xv.z * w;
      acc[v].w += xv.w * w;
    }
  }
  {
    float w = dinv[n];
    w = w * w;
    const float4* hp = (const float4*)(h + (size_t)n * ELEMS);
#pragma unroll
    for (int v = 0; v < V; v++) {
      float4 xv = hp[tid + v * 256];
      acc[v].x += xv.x * w;
      acc[v].y += xv.y * w;
      acc[v].z += xv.z * w;
      acc[v].w += xv.w * w;
    }
  }
  float4* op = (float4*)(out + (size_t)n * ELEMS);
#pragma unroll
  for (int v = 0; v < V; v++) {
    int e0 = (tid + v * 256) * 4;
    float4 r;
    r.x = fmaxf(acc[v].x + bias[(e0 + 0) & (C - 1)], 0.f);
    r.y = fmaxf(acc[v].y + bias[(e0 + 1) & (C - 1)], 0.f);
    r.z = fmaxf(acc[v].z + bias[(e0 + 2) & (C - 1)], 0.f);
    r.w = fmaxf(acc[v].w + bias[(e0 + 3) & (C - 1)], 0.f);
    op[tid + v * 256] = r;
  }
}

// K (O,I,W) -> Kt[(i*3+w)*C + o]
template <int C>
__global__ __launch_bounds__(256) void ktT_kernel(const float* __restrict__ K,
                                                  float* __restrict__ Kt) {
  int idx = blockIdx.x * 256 + threadIdx.x;
  if (idx < C * C * 3) {
    int w = idx % 3;
    int i = (idx / 3) % C;
    int o = idx / (3 * C);
    Kt[(i * 3 + w) * C + o] = K[idx];
  }
}

// temporal conv K=3 SAME over t, per node. X,Y: (N,16,C). Kt: [(i*3+w)*C+o]
template <int C, int TPT>
__global__ __launch_bounds__(256) void tconv_kernel(const float* __restrict__ X,
                                                    const float* __restrict__ Kt,
                                                    const float* __restrict__ kb,
                                                    float* __restrict__ Y) {
  __shared__ float xs[C * 20];  // [i][t+1], rows padded to 20 floats (16B-aligned t0)
  int n = blockIdx.x, tid = threadIdx.x;
  const float* xn = X + (size_t)n * SEQ * C;
  for (int idx = tid; idx < SEQ * C; idx += 256) {
    int t = idx / C, i = idx % C;
    xs[i * 20 + t + 1] = xn[idx];
  }
  for (int i = tid; i < C; i += 256) {
    xs[i * 20 + 0] = 0.f;
    xs[i * 20 + 17] = 0.f;
    xs[i * 20 + 18] = 0.f;
    xs[i * 20 + 19] = 0.f;
  }
  __syncthreads();
  int o = tid % C;
  int t0 = (tid / C) * TPT;
  float acc[TPT];
#pragma unroll
  for (int j = 0; j < TPT; j++) acc[j] = 0.f;
  for (int i = 0; i < C; i++) {
    const float4* xp4 = (const float4*)(xs + i * 20 + t0);  // aligned: 20*i + t0 % 4 == 0
    float xv[12];
    float4 a0 = xp4[0], a1 = xp4[1];
    xv[0] = a0.x; xv[1] = a0.y; xv[2] = a0.z; xv[3] = a0.w;
    xv[4] = a1.x; xv[5] = a1.y;
    if constexpr (TPT == 8) {
      float4 a2 = xp4[2];
      xv[6] = a1.z; xv[7] = a1.w;
      xv[8] = a2.x; xv[9] = a2.y;
    }
#pragma unroll
    for (int w = 0; w < 3; w++) {
      float k = Kt[(i * 3 + w) * C + o];
#pragma unroll
      for (int j = 0; j < TPT; j++) acc[j] += xv[j + w] * k;
    }
  }
  float kbv = kb[o];
#pragma unroll
  for (int j = 0; j < TPT; j++) {
    Y[(size_t)n * SEQ * C + (t0 + j) * C + o] = fmaxf(acc[j] + kbv, 0.f);
  }
}

// X (160000,64) @ W2 (64,128) -> Y (160000,128), 8 rows/block
__global__ __launch_bounds__(256) void lin2_kernel(const float* __restrict__ X,
                                                   const float* __restrict__ W,
                                                   float* __restrict__ Y) {
  __shared__ float Ws[HID * HID2];  // 32KB
  __shared__ float Xs[8][HID];
  int tid = threadIdx.x;
  int rowbase = blockIdx.x * 8;
  for (int k = tid; k < HID * HID2; k += 256) Ws[k] = W[k];
  for (int k = tid; k < 8 * HID; k += 256) {
    int r = k / HID, c = k % HID;
    Xs[r][c] = X[(size_t)(rowbase + r) * HID + c];
  }
  __syncthreads();
  int o = tid & 127;
  int rg = (tid >> 7) * 4;  // 0 or 4
  float a0 = 0.f, a1 = 0.f, a2 = 0.f, a3 = 0.f;
  for (int c = 0; c < HID; c++) {
    float w = Ws[c * HID2 + o];
    a0 += Xs[rg + 0][c] * w;
    a1 += Xs[rg + 1][c] * w;
    a2 += Xs[rg + 2][c] * w;
    a3 += Xs[rg + 3][c] * w;
  }
  Y[(size_t)(rowbase + rg + 0) * HID2 + o] = a0;
  Y[(size_t)(rowbase + rg + 1) * HID2 + o] = a1;
  Y[(size_t)(rowbase + rg + 2) * HID2 + o] = a2;
  Y[(size_t)(rowbase + rg + 3) * HID2 + o] = a3;
}

// head: last=H[:,15,:]; z=relu(last@F1+fb1); pred=z@F2+fb2; softplus
__global__ __launch_bounds__(64) void fc_kernel(const float* __restrict__ H,
                                                const float* __restrict__ F1,
                                                const float* __restrict__ fb1,
                                                const float* __restrict__ F2,
                                                const float* __restrict__ fb2,
                                                float* __restrict__ out) {
  __shared__ float last[HID2];
  __shared__ float zs[64];
  int n = blockIdx.x, tid = threadIdx.x;
  const float* hp = H + (size_t)n * SEQ * HID2 + 15 * HID2;
  last[tid] = hp[tid];
  last[tid + 64] = hp[tid + 64];
  __syncthreads();
  float acc = fb1[tid];
  for (int c = 0; c < HID2; c++) acc += last[c] * F1[c * 64 + tid];
  zs[tid] = fmaxf(acc, 0.f);
  __syncthreads();
  if (tid < 12) {
    float p = fb2[tid];
    for (int c = 0; c < 64; c++) p += zs[c] * F2[c * 12 + tid];
    float sp = fmaxf(p, 0.f) + log1pf(expf(-fabsf(p)));
    out[(size_t)n * 12 + tid] = sp;
  }
}

// ---------------- launch ----------------

extern "C" void kernel_launch(void* const* d_in, const int* in_sizes, int n_in,
                              void* d_out, int out_size, void* d_ws, size_t ws_size,
                              hipStream_t stream) {
  const float* x = (const float*)d_in[0];
  const int* edge = (const int*)d_in[1];
  const float* W1 = (const float*)d_in[2];
  const float* b1 = (const float*)d_in[3];
  const float* K1 = (const float*)d_in[4];
  const float* kb1 = (const float*)d_in[5];
  const float* W2 = (const float*)d_in[6];
  const float* b2 = (const float*)d_in[7];
  const float* K2 = (const float*)d_in[8];
  const float* kb2 = (const float*)d_in[9];
  const float* F1 = (const float*)d_in[10];
  const float* fb1 = (const float*)d_in[11];
  const float* F2 = (const float*)d_in[12];
  const float* fb2 = (const float*)d_in[13];
  float* out = (float*)d_out;

  char* ws = (char*)d_ws;
  size_t p = 0;
  auto alloc = [&](size_t bytes) -> char* {
    char* r = ws + p;
    p = (p + bytes + 255) & ~(size_t)255;
    return r;
  };
  float* A = (float*)alloc(40960000);   // lin1 out / tconv1 out; D overlaps [A,B)
  float* B = (float*)alloc(40960000);   // agg1 out
  float* Cb = (float*)alloc(81920000);  // lin2 out / tconv2 out
  float* D = A;                         // agg2 out (A,B dead by then; contiguous 82MB)
  int* counts = (int*)alloc(N_NODES * 4);
  int* offsets = (int*)alloc((N_NODES + 1) * 4);
  int* cursor = (int*)alloc(N_NODES * 4);
  float* dinv = (float*)alloc(N_NODES * 4);
  int* csr_src = (int*)alloc(N_EDGES * 4);
  float* csr_norm = (float*)alloc(N_EDGES * 4);
  float* Kt1 = (float*)alloc(HID * HID * 3 * 4);
  float* Kt2 = (float*)alloc(HID2 * HID2 * 3 * 4);
  (void)ws_size;
  (void)in_sizes;
  (void)n_in;
  (void)out_size;

  const int* src = edge;
  const int* dst = edge + N_EDGES;

  hipMemsetAsync(counts, 0, N_NODES * 4, stream);
  hist_kernel<<<(N_EDGES + 255) / 256, 256, 0, stream>>>(dst, counts);
  scan_kernel<<<1, 256, 0, stream>>>(counts, offsets, cursor, dinv);
  scatter_kernel<<<(N_EDGES + 255) / 256, 256, 0, stream>>>(src, dst, dinv, cursor, csr_src,
                                                            csr_norm);
  ktT_kernel<HID><<<(HID * HID * 3 + 255) / 256, 256, 0, stream>>>(K1, Kt1);
  ktT_kernel<HID2><<<(HID2 * HID2 * 3 + 255) / 256, 256, 0, stream>>>(K2, Kt2);

  lin1_kernel<<<40000, 256, 0, stream>>>(x, W1, A);
  agg_kernel<HID><<<N_NODES, 256, 0, stream>>>(A, csr_src, csr_norm, offsets, dinv, b1, B);
  tconv_kernel<HID, 4><<<N_NODES, 256, 0, stream>>>(B, Kt1, kb1, A);
  lin2_kernel<<<20000, 256, 0, stream>>>(A, W2, Cb);
  agg_kernel<HID2><<<N_NODES, 256, 0, stream>>>(Cb, csr_src, csr_norm, offsets, dinv, b2, D);
  tconv_kernel<HID2, 8><<<N_NODES, 256, 0, stream>>>(D, Kt2, kb2, Cb);
  fc_kernel<<<N_NODES, 64, 0, stream>>>(Cb, F1, fb1, F2, fb2, out);
}

// Round 4
// 648.005 us; speedup vs baseline: 1.3960x; 1.3960x over previous
//
#include <hip/hip_runtime.h>
#include <math.h>

#define N_NODES 10000
#define N_EDGES 160000
#define SEQ 16
#define F_INC 4
#define HID 64
#define HID2 128

// ---------------- graph preprocessing ----------------

__global__ __launch_bounds__(256) void hist_kernel(const int* __restrict__ dst,
                                                   int* __restrict__ counts) {
  int e = blockIdx.x * 256 + threadIdx.x;
  if (e < N_EDGES) atomicAdd(&counts[dst[e]], 1);
}

__global__ __launch_bounds__(256) void scan_kernel(const int* __restrict__ counts,
                                                   int* __restrict__ offsets,
                                                   int* __restrict__ cursor,
                                                   float* __restrict__ dinv) {
  __shared__ int partial[256];
  const int CHUNK = 40;  // 256*40 = 10240 >= 10000
  int tid = threadIdx.x;
  int base = tid * CHUNK;
  int s = 0;
  for (int k = 0; k < CHUNK; k++) {
    int idx = base + k;
    if (idx < N_NODES) s += counts[idx];
  }
  partial[tid] = s;
  __syncthreads();
  for (int d = 1; d < 256; d <<= 1) {
    int t = (tid >= d) ? partial[tid - d] : 0;
    __syncthreads();
    partial[tid] += t;
    __syncthreads();
  }
  int run = (tid == 0) ? 0 : partial[tid - 1];
  for (int k = 0; k < CHUNK; k++) {
    int idx = base + k;
    if (idx < N_NODES) {
      offsets[idx] = run;
      cursor[idx] = run;
      dinv[idx] = rsqrtf((float)counts[idx] + 1.0f);
      run += counts[idx];
    }
  }
  if (tid == 255) offsets[N_NODES] = partial[255];
}

__global__ __launch_bounds__(256) void scatter_kernel(const int* __restrict__ src,
                                                      const int* __restrict__ dst,
                                                      const float* __restrict__ dinv,
                                                      int* __restrict__ cursor,
                                                      int* __restrict__ csr_src,
                                                      float* __restrict__ csr_norm) {
  int e = blockIdx.x * 256 + threadIdx.x;
  if (e < N_EDGES) {
    int d = dst[e];
    int s = src[e];
    int pos = atomicAdd(&cursor[d], 1);
    csr_src[pos] = s;
    csr_norm[pos] = dinv[s] * dinv[d];
  }
}

// K (O,I,W) -> Kt[(i*3+w)*C + o]
template <int C>
__global__ __launch_bounds__(256) void ktT_kernel(const float* __restrict__ K,
                                                  float* __restrict__ Kt) {
  int idx = blockIdx.x * 256 + threadIdx.x;
  if (idx < C * C * 3) {
    int w = idx % 3;
    int i = (idx / 3) % C;
    int o = idx / (3 * C);
    Kt[(i * 3 + w) * C + o] = K[idx];
  }
}

// ---------------- aggregation (agg-first: agg(x)@W == agg(x@W)) ----------------

// 4-channel agg on raw x: 16 threads per node (one float4 each), 16 nodes/block.
__global__ __launch_bounds__(256) void agg4_kernel(const float* __restrict__ x,
                                                   const int* __restrict__ csr_src,
                                                   const float* __restrict__ csr_norm,
                                                   const int* __restrict__ offsets,
                                                   const float* __restrict__ dinv,
                                                   float* __restrict__ out) {
  int tid = threadIdx.x;
  int n = blockIdx.x * 16 + (tid >> 4);  // grid 625*16 = 10000 exactly
  int v = tid & 15;                      // float4 index within 64 floats
  int beg = offsets[n], end = offsets[n + 1];
  float4 acc = make_float4(0.f, 0.f, 0.f, 0.f);
  for (int e = beg; e < end; ++e) {
    int s = csr_src[e];
    float w = csr_norm[e];
    float4 xv = ((const float4*)(x + (size_t)s * 64))[v];
    acc.x += xv.x * w;
    acc.y += xv.y * w;
    acc.z += xv.z * w;
    acc.w += xv.w * w;
  }
  {
    float w = dinv[n];
    w = w * w;
    float4 xv = ((const float4*)(x + (size_t)n * 64))[v];
    acc.x += xv.x * w;
    acc.y += xv.y * w;
    acc.z += xv.z * w;
    acc.w += xv.w * w;
  }
  ((float4*)(out + (size_t)n * 64))[v] = acc;
}

// C-channel raw agg (no bias/relu): one block per node, 256 threads, float4 each.
template <int C>
__global__ __launch_bounds__(256) void aggC_kernel(const float* __restrict__ h,
                                                   const int* __restrict__ csr_src,
                                                   const float* __restrict__ csr_norm,
                                                   const int* __restrict__ offsets,
                                                   const float* __restrict__ dinv,
                                                   float* __restrict__ out) {
  constexpr int ELEMS = SEQ * C;  // 1024 for C=64
  constexpr int V = ELEMS / 1024;
  int n = blockIdx.x, tid = threadIdx.x;
  int beg = offsets[n], end = offsets[n + 1];
  float4 acc[V];
#pragma unroll
  for (int v = 0; v < V; v++) acc[v] = make_float4(0.f, 0.f, 0.f, 0.f);
  for (int e = beg; e < end; ++e) {
    int s = csr_src[e];
    float w = csr_norm[e];
    const float4* hp = (const float4*)(h + (size_t)s * ELEMS);
#pragma unroll
    for (int v = 0; v < V; v++) {
      float4 xv = hp[tid + v * 256];
      acc[v].x += xv.x * w;
      acc[v].y += xv.y * w;
      acc[v].z += xv.z * w;
      acc[v].w += xv.w * w;
    }
  }
  {
    float w = dinv[n];
    w = w * w;
    const float4* hp = (const float4*)(h + (size_t)n * ELEMS);
#pragma unroll
    for (int v = 0; v < V; v++) {
      float4 xv = hp[tid + v * 256];
      acc[v].x += xv.x * w;
      acc[v].y += xv.y * w;
      acc[v].z += xv.z * w;
      acc[v].w += xv.w * w;
    }
  }
  float4* op = (float4*)(out + (size_t)n * ELEMS);
#pragma unroll
  for (int v = 0; v < V; v++) op[tid + v * 256] = acc[v];
}

// ---------------- linear layers (bias + relu fused) ----------------

// aggX (N,16,4) @ W1 (4,64) + b1, relu -> H (N,16,64)
__global__ __launch_bounds__(256) void linw1_kernel(const float* __restrict__ AX,
                                                    const float* __restrict__ W,
                                                    const float* __restrict__ b,
                                                    float* __restrict__ H) {
  int idx = blockIdx.x * 256 + threadIdx.x;  // exactly 10000*16*64
  int o = idx & 63;
  int nt = idx >> 6;
  const float* xp = AX + (size_t)nt * 4;
  float acc = b[o] + xp[0] * W[o] + xp[1] * W[64 + o] + xp[2] * W[128 + o] + xp[3] * W[192 + o];
  H[idx] = fmaxf(acc, 0.f);
}

// X (160000,64) @ W2 (64,128) + b2, relu -> Y (160000,128), 8 rows/block
__global__ __launch_bounds__(256) void linw2_kernel(const float* __restrict__ X,
                                                    const float* __restrict__ W,
                                                    const float* __restrict__ b,
                                                    float* __restrict__ Y) {
  __shared__ float Ws[HID * HID2];  // 32KB
  __shared__ float Xs[8][HID];
  int tid = threadIdx.x;
  int rowbase = blockIdx.x * 8;
  for (int k = tid; k < HID * HID2; k += 256) Ws[k] = W[k];
  for (int k = tid; k < 8 * HID; k += 256) {
    int r = k / HID, c = k % HID;
    Xs[r][c] = X[(size_t)(rowbase + r) * HID + c];
  }
  __syncthreads();
  int o = tid & 127;
  int rg = (tid >> 7) * 4;  // 0 or 4
  float a0 = 0.f, a1 = 0.f, a2 = 0.f, a3 = 0.f;
  for (int c = 0; c < HID; c++) {
    float w = Ws[c * HID2 + o];
    a0 += Xs[rg + 0][c] * w;
    a1 += Xs[rg + 1][c] * w;
    a2 += Xs[rg + 2][c] * w;
    a3 += Xs[rg + 3][c] * w;
  }
  float bv = b[o];
  Y[(size_t)(rowbase + rg + 0) * HID2 + o] = fmaxf(a0 + bv, 0.f);
  Y[(size_t)(rowbase + rg + 1) * HID2 + o] = fmaxf(a1 + bv, 0.f);
  Y[(size_t)(rowbase + rg + 2) * HID2 + o] = fmaxf(a2 + bv, 0.f);
  Y[(size_t)(rowbase + rg + 3) * HID2 + o] = fmaxf(a3 + bv, 0.f);
}

// ---------------- temporal conv, TPT=16 (one thread = one (node,o), all t) ----------------

template <int C, int NPB>
__global__ __launch_bounds__(256) void tconv16_kernel(const float* __restrict__ X,
                                                      const float* __restrict__ Kt,
                                                      const float* __restrict__ kb,
                                                      float* __restrict__ Y) {
  __shared__ float xs[NPB * C * 20];  // per node: [i][t+1], rows padded to 20 floats
  int tid = threadIdx.x;
  int nb = blockIdx.x * NPB;
  for (int idx = tid; idx < NPB * SEQ * C; idx += 256) {
    int node = idx / (SEQ * C);
    int rem = idx - node * SEQ * C;
    int t = rem / C, i = rem % C;
    xs[node * C * 20 + i * 20 + t + 1] = X[(size_t)(nb + node) * SEQ * C + rem];
  }
  {  // zero the pads: NPB*C == 256 exactly for both instantiations
    int node = tid / C, i = tid % C;
    float* row = xs + node * C * 20 + i * 20;
    row[0] = 0.f;
    row[17] = 0.f;
    row[18] = 0.f;
    row[19] = 0.f;
  }
  __syncthreads();
  int o = tid % C;
  int node = tid / C;
  const float* xsn = xs + node * C * 20;
  float acc[SEQ];
#pragma unroll
  for (int j = 0; j < SEQ; j++) acc[j] = 0.f;
  for (int i = 0; i < C; i++) {
    const float4* r4 = (const float4*)(xsn + i * 20);
    float4 a0 = r4[0], a1 = r4[1], a2 = r4[2], a3 = r4[3];
    float2 a4 = ((const float2*)r4)[8];  // floats 16,17
    float f[18] = {a0.x, a0.y, a0.z, a0.w, a1.x, a1.y, a1.z, a1.w, a2.x,
                   a2.y, a2.z, a2.w, a3.x, a3.y, a3.z, a3.w, a4.x, a4.y};
    const float* kp = Kt + (size_t)(i * 3) * C + o;
#pragma unroll
    for (int w = 0; w < 3; w++) {
      float k = kp[w * C];
#pragma unroll
      for (int j = 0; j < SEQ; j++) acc[j] = fmaf(f[j + w], k, acc[j]);
    }
  }
  float kbv = kb[o];
  float* yp = Y + (size_t)(nb + node) * SEQ * C + o;
#pragma unroll
  for (int j = 0; j < SEQ; j++) yp[j * C] = fmaxf(acc[j] + kbv, 0.f);
}

// ---------------- head ----------------

__global__ __launch_bounds__(64) void fc_kernel(const float* __restrict__ H,
                                                const float* __restrict__ F1,
                                                const float* __restrict__ fb1,
                                                const float* __restrict__ F2,
                                                const float* __restrict__ fb2,
                                                float* __restrict__ out) {
  __shared__ float last[HID2];
  __shared__ float zs[64];
  int n = blockIdx.x, tid = threadIdx.x;
  const float* hp = H + (size_t)n * SEQ * HID2 + 15 * HID2;
  last[tid] = hp[tid];
  last[tid + 64] = hp[tid + 64];
  __syncthreads();
  float acc = fb1[tid];
  for (int c = 0; c < HID2; c++) acc += last[c] * F1[c * 64 + tid];
  zs[tid] = fmaxf(acc, 0.f);
  __syncthreads();
  if (tid < 12) {
    float p = fb2[tid];
    for (int c = 0; c < 64; c++) p += zs[c] * F2[c * 12 + tid];
    float sp = fmaxf(p, 0.f) + log1pf(expf(-fabsf(p)));
    out[(size_t)n * 12 + tid] = sp;
  }
}

// ---------------- launch ----------------

extern "C" void kernel_launch(void* const* d_in, const int* in_sizes, int n_in,
                              void* d_out, int out_size, void* d_ws, size_t ws_size,
                              hipStream_t stream) {
  const float* x = (const float*)d_in[0];
  const int* edge = (const int*)d_in[1];
  const float* W1 = (const float*)d_in[2];
  const float* b1 = (const float*)d_in[3];
  const float* K1 = (const float*)d_in[4];
  const float* kb1 = (const float*)d_in[5];
  const float* W2 = (const float*)d_in[6];
  const float* b2 = (const float*)d_in[7];
  const float* K2 = (const float*)d_in[8];
  const float* kb2 = (const float*)d_in[9];
  const float* F1 = (const float*)d_in[10];
  const float* fb1 = (const float*)d_in[11];
  const float* F2 = (const float*)d_in[12];
  const float* fb2 = (const float*)d_in[13];
  float* out = (float*)d_out;

  char* ws = (char*)d_ws;
  size_t p = 0;
  auto alloc = [&](size_t bytes) -> char* {
    char* r = ws + p;
    p = (p + bytes + 255) & ~(size_t)255;
    return r;
  };
  // bufX: linw1 out; agg2 out; [with bufY] tconv2 out (82MB span)
  // bufY: tconv1 out
  float* bufX = (float*)alloc(40960000);
  float* bufY = (float*)alloc(40960000);
  float* Cb = (float*)alloc(81920000);  // linw2 out (tconv2 input)
  float* D = bufX;                      // tconv2 out spans bufX+bufY (both dead)
  float* aggX1 = (float*)alloc(N_NODES * 64 * 4);
  int* counts = (int*)alloc(N_NODES * 4);
  int* offsets = (int*)alloc((N_NODES + 1) * 4);
  int* cursor = (int*)alloc(N_NODES * 4);
  float* dinv = (float*)alloc(N_NODES * 4);
  int* csr_src = (int*)alloc(N_EDGES * 4);
  float* csr_norm = (float*)alloc(N_EDGES * 4);
  float* Kt1 = (float*)alloc(HID * HID * 3 * 4);
  float* Kt2 = (float*)alloc(HID2 * HID2 * 3 * 4);
  (void)ws_size;
  (void)in_sizes;
  (void)n_in;
  (void)out_size;

  const int* src = edge;
  const int* dst = edge + N_EDGES;

  hipMemsetAsync(counts, 0, N_NODES * 4, stream);
  hist_kernel<<<(N_EDGES + 255) / 256, 256, 0, stream>>>(dst, counts);
  scan_kernel<<<1, 256, 0, stream>>>(counts, offsets, cursor, dinv);
  scatter_kernel<<<(N_EDGES + 255) / 256, 256, 0, stream>>>(src, dst, dinv, cursor, csr_src,
                                                            csr_norm);
  ktT_kernel<HID><<<(HID * HID * 3 + 255) / 256, 256, 0, stream>>>(K1, Kt1);
  ktT_kernel<HID2><<<(HID2 * HID2 * 3 + 255) / 256, 256, 0, stream>>>(K2, Kt2);

  // layer 1: agg(x) -> @W1+b1,relu -> tconv1
  agg4_kernel<<<625, 256, 0, stream>>>(x, csr_src, csr_norm, offsets, dinv, aggX1);
  linw1_kernel<<<40000, 256, 0, stream>>>(aggX1, W1, b1, bufX);
  tconv16_kernel<HID, 4><<<2500, 256, 0, stream>>>(bufX, Kt1, kb1, bufY);
  // layer 2: agg(tconv1) -> @W2+b2,relu -> tconv2
  aggC_kernel<HID><<<N_NODES, 256, 0, stream>>>(bufY, csr_src, csr_norm, offsets, dinv, bufX);
  linw2_kernel<<<20000, 256, 0, stream>>>(bufX, W2, b2, Cb);
  tconv16_kernel<HID2, 2><<<5000, 256, 0, stream>>>(Cb, Kt2, kb2, D);
  // head
  fc_kernel<<<N_NODES, 64, 0, stream>>>(D, F1, fb1, F2, fb2, out);
}

// Round 9
// 280.080 us; speedup vs baseline: 3.2298x; 2.3136x over previous
//
#include <hip/hip_runtime.h>
#include <math.h>

#define N_NODES 10000
#define N_EDGES 160000
#define SEQ 16
#define HID 64
#define HID2 128

// Only out[:, -1, :] of tconv2 feeds the head => compute:
//   layer1 (agg4/linw1) at t=13,14,15 ; tconv1 at t=14,15 ;
//   layer2 (agg2/lin2)  at t=14,15    ; tconv2 at t=15 only (fused with FC head).

// ---------------- graph preprocessing ----------------

__global__ __launch_bounds__(256) void hist_kernel(const int* __restrict__ dst,
                                                   int* __restrict__ counts) {
  int e = blockIdx.x * 256 + threadIdx.x;
  if (e < N_EDGES) atomicAdd(&counts[dst[e]], 1);
}

__global__ __launch_bounds__(256) void scan_kernel(const int* __restrict__ counts,
                                                   int* __restrict__ offsets,
                                                   int* __restrict__ cursor,
                                                   float* __restrict__ dinv) {
  __shared__ int partial[256];
  const int CHUNK = 40;  // 256*40 = 10240 >= 10000
  int tid = threadIdx.x;
  int base = tid * CHUNK;
  int s = 0;
  for (int k = 0; k < CHUNK; k++) {
    int idx = base + k;
    if (idx < N_NODES) s += counts[idx];
  }
  partial[tid] = s;
  __syncthreads();
  for (int d = 1; d < 256; d <<= 1) {
    int t = (tid >= d) ? partial[tid - d] : 0;
    __syncthreads();
    partial[tid] += t;
    __syncthreads();
  }
  int run = (tid == 0) ? 0 : partial[tid - 1];
  for (int k = 0; k < CHUNK; k++) {
    int idx = base + k;
    if (idx < N_NODES) {
      offsets[idx] = run;
      cursor[idx] = run;
      dinv[idx] = rsqrtf((float)counts[idx] + 1.0f);
      run += counts[idx];
    }
  }
  if (tid == 255) offsets[N_NODES] = partial[255];
}

__global__ __launch_bounds__(256) void scatter_kernel(const int* __restrict__ src,
                                                      const int* __restrict__ dst,
                                                      const float* __restrict__ dinv,
                                                      int* __restrict__ cursor,
                                                      int* __restrict__ csr_src,
                                                      float* __restrict__ csr_norm) {
  int e = blockIdx.x * 256 + threadIdx.x;
  if (e < N_EDGES) {
    int d = dst[e];
    int s = src[e];
    int pos = atomicAdd(&cursor[d], 1);
    csr_src[pos] = s;
    csr_norm[pos] = dinv[s] * dinv[d];
  }
}

// K (O,I,W) -> Kt[(i*3+w)*C + o]
template <int C>
__global__ __launch_bounds__(256) void ktT_kernel(const float* __restrict__ K,
                                                  float* __restrict__ Kt) {
  int idx = blockIdx.x * 256 + threadIdx.x;
  if (idx < C * C * 3) {
    int w = idx % 3;
    int i = (idx / 3) % C;
    int o = idx / (3 * C);
    Kt[(i * 3 + w) * C + o] = K[idx];
  }
}

// ---------------- layer 1 (t = 13,14,15 only) ----------------

// 4-ch agg on raw x at t in {13,14,15}: thread = (n,t'), t'=t-13. aggX: [n][3][4]
__global__ __launch_bounds__(256) void agg4_3t_kernel(const float* __restrict__ x,
                                                      const int* __restrict__ csr_src,
                                                      const float* __restrict__ csr_norm,
                                                      const int* __restrict__ offsets,
                                                      const float* __restrict__ dinv,
                                                      float* __restrict__ aggX) {
  int idx = blockIdx.x * 256 + threadIdx.x;
  if (idx >= N_NODES * 3) return;
  int n = idx / 3;
  int t = 13 + (idx - n * 3);
  int beg = offsets[n], end = offsets[n + 1];
  float4 acc = make_float4(0.f, 0.f, 0.f, 0.f);
  for (int e = beg; e < end; ++e) {
    int s = csr_src[e];
    float w = csr_norm[e];
    float4 xv = *(const float4*)(x + (size_t)s * 64 + t * 4);
    acc.x += xv.x * w;
    acc.y += xv.y * w;
    acc.z += xv.z * w;
    acc.w += xv.w * w;
  }
  {
    float w = dinv[n];
    w = w * w;
    float4 xv = *(const float4*)(x + (size_t)n * 64 + t * 4);
    acc.x += xv.x * w;
    acc.y += xv.y * w;
    acc.z += xv.z * w;
    acc.w += xv.w * w;
  }
  *(float4*)(aggX + (size_t)idx * 4) = acc;
}

// aggX (N,3,4) @ W1 (4,64) + b1, relu -> H1 (N,3,64). 1.92M threads.
__global__ __launch_bounds__(256) void linw1_3t_kernel(const float* __restrict__ AX,
                                                       const float* __restrict__ W,
                                                       const float* __restrict__ b,
                                                       float* __restrict__ H1) {
  int idx = blockIdx.x * 256 + threadIdx.x;  // exactly 10000*3*64
  int o = idx & 63;
  int r = idx >> 6;  // n*3 + t'
  float4 xv = *(const float4*)(AX + (size_t)r * 4);
  float acc = b[o] + xv.x * W[o] + xv.y * W[64 + o] + xv.z * W[128 + o] + xv.w * W[192 + o];
  H1[idx] = fmaxf(acc, 0.f);
}

// tconv1 at t=14,15. H1: [n][3][64] (t=13,14,15). T1: [n][2][64]. 2 nodes/block.
__global__ __launch_bounds__(256) void tconv1_2t_kernel(const float* __restrict__ H1,
                                                        const float* __restrict__ Kt1,
                                                        const float* __restrict__ kb,
                                                        float* __restrict__ T1) {
  __shared__ float ls[2 * 192];
  int tid = threadIdx.x;
  int nb = blockIdx.x * 2;
  for (int i2 = tid; i2 < 384; i2 += 256) ls[i2] = H1[(size_t)nb * 192 + i2];
  __syncthreads();
  int nl = tid >> 7;
  int lane = tid & 127;
  int tt = lane >> 6;  // wave-uniform
  int o = lane & 63;
  const float* L = ls + nl * 192;
  float acc = kb[o];
  if (tt == 0) {  // out t=14: in t=13,14,15 (rows 0,1,2), w=0,1,2
    for (int i = 0; i < 64; i++) {
      float k0 = Kt1[(i * 3 + 0) * 64 + o];
      float k1 = Kt1[(i * 3 + 1) * 64 + o];
      float k2 = Kt1[(i * 3 + 2) * 64 + o];
      acc += L[i] * k0 + L[64 + i] * k1 + L[128 + i] * k2;
    }
  } else {  // out t=15: in t=14,15 (rows 1,2), w=0,1; w=2 hits pad
    for (int i = 0; i < 64; i++) {
      float k0 = Kt1[(i * 3 + 0) * 64 + o];
      float k1 = Kt1[(i * 3 + 1) * 64 + o];
      acc += L[64 + i] * k0 + L[128 + i] * k1;
    }
  }
  T1[(size_t)(nb + nl) * 128 + tt * 64 + o] = fmaxf(acc, 0.f);
}

// ---------------- layer 2 (t = 14,15 only) ----------------

// agg over T1: [n][2][64] = 128 floats/node. 8 nodes/block, 32 threads (float4) each.
__global__ __launch_bounds__(256) void agg2_kernel(const float* __restrict__ T1,
                                                   const int* __restrict__ csr_src,
                                                   const float* __restrict__ csr_norm,
                                                   const int* __restrict__ offsets,
                                                   const float* __restrict__ dinv,
                                                   float* __restrict__ A2) {
  int tid = threadIdx.x;
  int n = blockIdx.x * 8 + (tid >> 5);
  int v = tid & 31;
  int beg = offsets[n], end = offsets[n + 1];
  float4 acc = make_float4(0.f, 0.f, 0.f, 0.f);
  for (int e = beg; e < end; ++e) {
    int s = csr_src[e];
    float w = csr_norm[e];
    float4 tv = ((const float4*)(T1 + (size_t)s * 128))[v];
    acc.x += tv.x * w;
    acc.y += tv.y * w;
    acc.z += tv.z * w;
    acc.w += tv.w * w;
  }
  {
    float w = dinv[n];
    w = w * w;
    float4 tv = ((const float4*)(T1 + (size_t)n * 128))[v];
    acc.x += tv.x * w;
    acc.y += tv.y * w;
    acc.z += tv.z * w;
    acc.w += tv.w * w;
  }
  ((float4*)(A2 + (size_t)n * 128))[v] = acc;
}

// A2 (N,2,64) @ W2 (64,128) + b2, relu -> H2 (N,2,128). Thread does both tt.
__global__ __launch_bounds__(256) void lin2_2t_kernel(const float* __restrict__ A2,
                                                      const float* __restrict__ W2,
                                                      const float* __restrict__ b2,
                                                      float* __restrict__ H2) {
  int idx = blockIdx.x * 256 + threadIdx.x;  // exactly 10000*128
  int o = idx & 127;
  int n = idx >> 7;
  const float* a = A2 + (size_t)n * 128;
  float acc0 = b2[o], acc1 = acc0;
  for (int c = 0; c < 64; c++) {
    float w = W2[c * 128 + o];
    acc0 += a[c] * w;
    acc1 += a[64 + c] * w;
  }
  H2[(size_t)n * 256 + o] = fmaxf(acc0, 0.f);
  H2[(size_t)n * 256 + 128 + o] = fmaxf(acc1, 0.f);
}

// tconv2 at t=15 + FC head + softplus. 8 nodes/block; each thread serves 4 nodes.
__global__ __launch_bounds__(256) void tconv2fc_kernel(const float* __restrict__ H2,
                                                       const float* __restrict__ Kt2,
                                                       const float* __restrict__ kb2,
                                                       const float* __restrict__ F1,
                                                       const float* __restrict__ fb1,
                                                       const float* __restrict__ F2,
                                                       const float* __restrict__ fb2,
                                                       float* __restrict__ out) {
  __shared__ float ls2[8 * 256];    // 8 nodes x (2 t x 128 ch)
  __shared__ float lastv[8 * 128];  // relu(tconv2 t=15)
  __shared__ float zs[8 * 64];
  int tid = threadIdx.x;
  int nb = blockIdx.x * 8;
  for (int i2 = tid; i2 < 2048; i2 += 256) ls2[i2] = H2[(size_t)nb * 256 + i2];
  __syncthreads();
  int half = tid >> 7;  // serves local nodes half, half+2, half+4, half+6
  int o = tid & 127;
  float acc[4];
#pragma unroll
  for (int k = 0; k < 4; k++) acc[k] = kb2[o];
  for (int i = 0; i < 128; i++) {
    float k0 = Kt2[(i * 3 + 0) * 128 + o];  // w=0 -> t=14 (row 0)
    float k1 = Kt2[(i * 3 + 1) * 128 + o];  // w=1 -> t=15 (row 1); w=2 -> pad
#pragma unroll
    for (int k = 0; k < 4; k++) {
      const float* L = ls2 + (half + 2 * k) * 256;
      acc[k] += L[i] * k0 + L[128 + i] * k1;
    }
  }
#pragma unroll
  for (int k = 0; k < 4; k++) lastv[(half + 2 * k) * 128 + o] = fmaxf(acc[k], 0.f);
  __syncthreads();
#pragma unroll
  for (int rep = 0; rep < 2; rep++) {
    int zi = tid + rep * 256;  // 512 z values: 8 nodes x 64
    int node = zi >> 6;
    int oz = zi & 63;
    float z = fb1[oz];
    const float* Lv = lastv + node * 128;
    for (int c = 0; c < HID2; c++) z += Lv[c] * F1[c * 64 + oz];
    zs[zi] = fmaxf(z, 0.f);
  }
  __syncthreads();
  if (tid < 96) {
    int node = tid / 12;
    int oo = tid - node * 12;
    float p = fb2[oo];
    const float* Z = zs + node * 64;
    for (int c = 0; c < 64; c++) p += Z[c] * F2[c * 12 + oo];
    float sp = fmaxf(p, 0.f) + log1pf(expf(-fabsf(p)));
    out[(size_t)(nb + node) * 12 + oo] = sp;
  }
}

// ---------------- launch ----------------

extern "C" void kernel_launch(void* const* d_in, const int* in_sizes, int n_in,
                              void* d_out, int out_size, void* d_ws, size_t ws_size,
                              hipStream_t stream) {
  const float* x = (const float*)d_in[0];
  const int* edge = (const int*)d_in[1];
  const float* W1 = (const float*)d_in[2];
  const float* b1 = (const float*)d_in[3];
  const float* K1 = (const float*)d_in[4];
  const float* kb1 = (const float*)d_in[5];
  const float* W2 = (const float*)d_in[6];
  const float* b2 = (const float*)d_in[7];
  const float* K2 = (const float*)d_in[8];
  const float* kb2 = (const float*)d_in[9];
  const float* F1 = (const float*)d_in[10];
  const float* fb1 = (const float*)d_in[11];
  const float* F2 = (const float*)d_in[12];
  const float* fb2 = (const float*)d_in[13];
  float* out = (float*)d_out;

  char* ws = (char*)d_ws;
  size_t p = 0;
  auto alloc = [&](size_t bytes) -> char* {
    char* r = ws + p;
    p = (p + bytes + 255) & ~(size_t)255;
    return r;
  };
  float* aggX = (float*)alloc(N_NODES * 3 * 4 * 4);   // (N,3,4)
  float* H1 = (float*)alloc(N_NODES * 3 * 64 * 4);    // (N,3,64)
  float* T1 = (float*)alloc(N_NODES * 2 * 64 * 4);    // (N,2,64)
  float* A2 = (float*)alloc(N_NODES * 2 * 64 * 4);    // (N,2,64)
  float* H2 = (float*)alloc(N_NODES * 2 * 128 * 4);   // (N,2,128)
  int* counts = (int*)alloc(N_NODES * 4);
  int* offsets = (int*)alloc((N_NODES + 1) * 4);
  int* cursor = (int*)alloc(N_NODES * 4);
  float* dinv = (float*)alloc(N_NODES * 4);
  int* csr_src = (int*)alloc(N_EDGES * 4);
  float* csr_norm = (float*)alloc(N_EDGES * 4);
  float* Kt1 = (float*)alloc(HID * HID * 3 * 4);
  float* Kt2 = (float*)alloc(HID2 * HID2 * 3 * 4);
  (void)ws_size;
  (void)in_sizes;
  (void)n_in;
  (void)out_size;

  const int* src = edge;
  const int* dst = edge + N_EDGES;

  hipMemsetAsync(counts, 0, N_NODES * 4, stream);
  hist_kernel<<<(N_EDGES + 255) / 256, 256, 0, stream>>>(dst, counts);
  scan_kernel<<<1, 256, 0, stream>>>(counts, offsets, cursor, dinv);
  scatter_kernel<<<(N_EDGES + 255) / 256, 256, 0, stream>>>(src, dst, dinv, cursor, csr_src,
                                                            csr_norm);
  ktT_kernel<HID><<<(HID * HID * 3 + 255) / 256, 256, 0, stream>>>(K1, Kt1);
  ktT_kernel<HID2><<<(HID2 * HID2 * 3 + 255) / 256, 256, 0, stream>>>(K2, Kt2);

  // layer 1 (t=13..15)
  agg4_3t_kernel<<<(N_NODES * 3 + 255) / 256, 256, 0, stream>>>(x, csr_src, csr_norm, offsets,
                                                                dinv, aggX);
  linw1_3t_kernel<<<N_NODES * 3 * 64 / 256, 256, 0, stream>>>(aggX, W1, b1, H1);
  tconv1_2t_kernel<<<N_NODES / 2, 256, 0, stream>>>(H1, Kt1, kb1, T1);
  // layer 2 (t=14,15)
  agg2_kernel<<<N_NODES / 8, 256, 0, stream>>>(T1, csr_src, csr_norm, offsets, dinv, A2);
  lin2_2t_kernel<<<N_NODES * 128 / 256, 256, 0, stream>>>(A2, W2, b2, H2);
  // tconv2 (t=15) + FC head
  tconv2fc_kernel<<<N_NODES / 8, 256, 0, stream>>>(H2, Kt2, kb2, F1, fb1, F2, fb2, out);
}

// Round 10
// 206.643 us; speedup vs baseline: 4.3776x; 1.3554x over previous
//
#include <hip/hip_runtime.h>
#include <math.h>

#define N_NODES 10000
#define N_EDGES 160000
#define SEQ 16
#define HID 64
#define HID2 128

// DCE: only out[:, -1, :] of tconv2 feeds the head => compute
//   layer1 (agg4/linw1) at t=13,14,15 ; tconv1 at t=14,15 ;
//   layer2 (agg2/lin2)  at t=14,15    ; tconv2 at t=15 (fused with FC head).
// 7 dispatches: memset, hist, scan, scatter+ktT, layer1(fused), agg2, layer2(fused).

// ---------------- graph preprocessing ----------------

__global__ __launch_bounds__(256) void hist_kernel(const int* __restrict__ dst,
                                                   int* __restrict__ counts) {
  int e = blockIdx.x * 256 + threadIdx.x;
  if (e < N_EDGES) atomicAdd(&counts[dst[e]], 1);
}

__global__ __launch_bounds__(1024) void scan_kernel(const int* __restrict__ counts,
                                                    int* __restrict__ offsets,
                                                    int* __restrict__ cursor,
                                                    float* __restrict__ dinv) {
  __shared__ int partial[1024];
  const int CHUNK = 10;  // 1024*10 = 10240 >= 10000
  int tid = threadIdx.x;
  int base = tid * CHUNK;
  int s = 0;
  for (int k = 0; k < CHUNK; k++) {
    int idx = base + k;
    if (idx < N_NODES) s += counts[idx];
  }
  partial[tid] = s;
  __syncthreads();
  for (int d = 1; d < 1024; d <<= 1) {
    int t = (tid >= d) ? partial[tid - d] : 0;
    __syncthreads();
    partial[tid] += t;
    __syncthreads();
  }
  int run = (tid == 0) ? 0 : partial[tid - 1];
  for (int k = 0; k < CHUNK; k++) {
    int idx = base + k;
    if (idx < N_NODES) {
      offsets[idx] = run;
      cursor[idx] = run;
      dinv[idx] = rsqrtf((float)counts[idx] + 1.0f);
      run += counts[idx];
    }
  }
  if (tid == 1023) offsets[N_NODES] = partial[1023];
}

// fused: blocks 0..624 scatter edges; 625..672 transpose K1; 673..864 transpose K2.
__global__ __launch_bounds__(256) void scatter_ktt_kernel(
    const int* __restrict__ src, const int* __restrict__ dst, const float* __restrict__ dinv,
    int* __restrict__ cursor, int* __restrict__ csr_src, float* __restrict__ csr_norm,
    const float* __restrict__ K1, float* __restrict__ Kt1, const float* __restrict__ K2,
    float* __restrict__ Kt2) {
  int b = blockIdx.x;
  int tid = threadIdx.x;
  if (b < 625) {
    int e = b * 256 + tid;  // 625*256 == 160000 exactly
    int d = dst[e];
    int s = src[e];
    int pos = atomicAdd(&cursor[d], 1);
    csr_src[pos] = s;
    csr_norm[pos] = dinv[s] * dinv[d];
  } else if (b < 673) {
    int idx = (b - 625) * 256 + tid;  // 48*256 == 12288 == 64*64*3 exactly
    int w = idx % 3;
    int i = (idx / 3) % HID;
    int o = idx / (3 * HID);
    Kt1[(i * 3 + w) * HID + o] = K1[idx];
  } else {
    int idx = (b - 673) * 256 + tid;  // 192*256 == 49152 == 128*128*3 exactly
    int w = idx % 3;
    int i = (idx / 3) % HID2;
    int o = idx / (3 * HID2);
    Kt2[(i * 3 + w) * HID2 + o] = K2[idx];
  }
}

// ---------------- layer 1 fused: agg4(t=13..15) -> @W1+b1,relu -> tconv1(t=14,15) ----------------
// 16 nodes/block, 625 blocks.

__global__ __launch_bounds__(256) void layer1_kernel(
    const float* __restrict__ x, const int* __restrict__ csr_src,
    const float* __restrict__ csr_norm, const int* __restrict__ offsets,
    const float* __restrict__ dinv, const float* __restrict__ W1, const float* __restrict__ b1,
    const float* __restrict__ Kt1, const float* __restrict__ kb1, float* __restrict__ T1) {
  __shared__ float aggXs[48 * 4];   // [row = n_local*3 + t'][4]
  __shared__ float H1s[16 * 192];   // [n_local][t'*64 + o]
  int tid = threadIdx.x;
  int nb = blockIdx.x * 16;
  // phase A: gather-agg, 48 rows (n_local, t) with t = 13 + row%3
  if (tid < 48) {
    int n = nb + tid / 3;
    int t = 13 + tid % 3;
    int beg = offsets[n], end = offsets[n + 1];
    float4 acc = make_float4(0.f, 0.f, 0.f, 0.f);
    for (int e = beg; e < end; ++e) {
      int s = csr_src[e];
      float w = csr_norm[e];
      float4 xv = *(const float4*)(x + (size_t)s * 64 + t * 4);
      acc.x += xv.x * w;
      acc.y += xv.y * w;
      acc.z += xv.z * w;
      acc.w += xv.w * w;
    }
    {
      float w = dinv[n];
      w = w * w;
      float4 xv = *(const float4*)(x + (size_t)n * 64 + t * 4);
      acc.x += xv.x * w;
      acc.y += xv.y * w;
      acc.z += xv.z * w;
      acc.w += xv.w * w;
    }
    *(float4*)(aggXs + tid * 4) = acc;
  }
  __syncthreads();
  // phase B: linw1 — 48 rows x 64 o = 3072 outputs, 12 per thread.
  // note row*64 == (row/3)*192 + (row%3)*64, so H1s[row*64+o] is [n_local][t'][o].
#pragma unroll
  for (int k = 0; k < 12; k++) {
    int idx = tid + k * 256;
    int row = idx >> 6;
    int o = idx & 63;
    const float* a = aggXs + row * 4;
    float acc = b1[o] + a[0] * W1[o] + a[1] * W1[64 + o] + a[2] * W1[128 + o] + a[3] * W1[192 + o];
    H1s[row * 64 + o] = fmaxf(acc, 0.f);
  }
  __syncthreads();
  // phase C: tconv1 at t=14,15. thread: (g = tid>>7, rem = tt*64+o); 8 nodes per thread
  // (nodes g, g+2, ..., g+14) so each Kt1 load feeds 8 FMAs.
  {
    int g = tid >> 7;
    int rem = tid & 127;
    int tt = rem >> 6;  // wave-uniform (wave0: tt=0, wave1: tt=1, ...)
    int o = rem & 63;
    float acc[8];
    float kbv = kb1[o];
#pragma unroll
    for (int j = 0; j < 8; j++) acc[j] = kbv;
    if (tt == 0) {  // out t=14: rows 0,1,2 with w=0,1,2
      for (int i = 0; i < 64; i++) {
        float k0 = Kt1[(i * 3 + 0) * 64 + o];
        float k1 = Kt1[(i * 3 + 1) * 64 + o];
        float k2 = Kt1[(i * 3 + 2) * 64 + o];
#pragma unroll
        for (int j = 0; j < 8; j++) {
          const float* L = H1s + (g + 2 * j) * 192;
          acc[j] += L[i] * k0 + L[64 + i] * k1 + L[128 + i] * k2;
        }
      }
    } else {  // out t=15: rows 1,2 with w=0,1 (w=2 hits pad)
      for (int i = 0; i < 64; i++) {
        float k0 = Kt1[(i * 3 + 0) * 64 + o];
        float k1 = Kt1[(i * 3 + 1) * 64 + o];
#pragma unroll
        for (int j = 0; j < 8; j++) {
          const float* L = H1s + (g + 2 * j) * 192;
          acc[j] += L[64 + i] * k0 + L[128 + i] * k1;
        }
      }
    }
#pragma unroll
    for (int j = 0; j < 8; j++) {
      T1[(size_t)(nb + g + 2 * j) * 128 + rem] = fmaxf(acc[j], 0.f);
    }
  }
}

// ---------------- agg2: gather T1 over edges (unchanged from validated R4 kernel) ----------------

__global__ __launch_bounds__(256) void agg2_kernel(const float* __restrict__ T1,
                                                   const int* __restrict__ csr_src,
                                                   const float* __restrict__ csr_norm,
                                                   const int* __restrict__ offsets,
                                                   const float* __restrict__ dinv,
                                                   float* __restrict__ A2) {
  int tid = threadIdx.x;
  int n = blockIdx.x * 8 + (tid >> 5);
  int v = tid & 31;
  int beg = offsets[n], end = offsets[n + 1];
  float4 acc = make_float4(0.f, 0.f, 0.f, 0.f);
  for (int e = beg; e < end; ++e) {
    int s = csr_src[e];
    float w = csr_norm[e];
    float4 tv = ((const float4*)(T1 + (size_t)s * 128))[v];
    acc.x += tv.x * w;
    acc.y += tv.y * w;
    acc.z += tv.z * w;
    acc.w += tv.w * w;
  }
  {
    float w = dinv[n];
    w = w * w;
    float4 tv = ((const float4*)(T1 + (size_t)n * 128))[v];
    acc.x += tv.x * w;
    acc.y += tv.y * w;
    acc.z += tv.z * w;
    acc.w += tv.w * w;
  }
  ((float4*)(A2 + (size_t)n * 128))[v] = acc;
}

// ---------------- layer 2 fused: lin2 -> tconv2(t=15) -> FC head -> softplus ----------------
// 8 nodes/block, 1250 blocks.

__global__ __launch_bounds__(256) void layer2_kernel(
    const float* __restrict__ A2, const float* __restrict__ W2, const float* __restrict__ b2,
    const float* __restrict__ Kt2, const float* __restrict__ kb2, const float* __restrict__ F1,
    const float* __restrict__ fb1, const float* __restrict__ F2, const float* __restrict__ fb2,
    float* __restrict__ out) {
  __shared__ float A2s[8 * 128];    // [n_local][tt*64 + c]
  __shared__ float H2s[8 * 256];    // [n_local][tt*128 + o]
  __shared__ float lastv[8 * 128];  // relu(tconv2 t=15)
  __shared__ float zs[8 * 64];
  int tid = threadIdx.x;
  int nb = blockIdx.x * 8;
  // stage A2
#pragma unroll
  for (int k = 0; k < 4; k++) A2s[tid + k * 256] = A2[(size_t)nb * 128 + tid + k * 256];
  __syncthreads();
  // lin2: 16 (n,tt) pairs x 128 o. thread: (o = tid&127, g = tid>>7), pairs g, g+2, ..., g+14.
  {
    int o = tid & 127;
    int g = tid >> 7;
    float acc[8];
    float bv = b2[o];
#pragma unroll
    for (int j = 0; j < 8; j++) acc[j] = bv;
    for (int c = 0; c < 64; c++) {
      float w = W2[c * 128 + o];
#pragma unroll
      for (int j = 0; j < 8; j++) {
        int p = g + 2 * j;  // pair: n_local = p>>1, tt = p&1
        acc[j] += A2s[(p >> 1) * 128 + (p & 1) * 64 + c] * w;
      }
    }
#pragma unroll
    for (int j = 0; j < 8; j++) {
      int p = g + 2 * j;
      H2s[(p >> 1) * 256 + (p & 1) * 128 + o] = fmaxf(acc[j], 0.f);
    }
  }
  __syncthreads();
  // tconv2 t=15: w=0 -> t=14 (row 0), w=1 -> t=15 (row 1), w=2 -> pad.
  {
    int half = tid >> 7;
    int o = tid & 127;
    float acc[4];
    float kbv = kb2[o];
#pragma unroll
    for (int k = 0; k < 4; k++) acc[k] = kbv;
    for (int i = 0; i < 128; i++) {
      float k0 = Kt2[(i * 3 + 0) * 128 + o];
      float k1 = Kt2[(i * 3 + 1) * 128 + o];
#pragma unroll
      for (int k = 0; k < 4; k++) {
        const float* L = H2s + (half + 2 * k) * 256;
        acc[k] += L[i] * k0 + L[128 + i] * k1;
      }
    }
#pragma unroll
    for (int k = 0; k < 4; k++) lastv[(half + 2 * k) * 128 + o] = fmaxf(acc[k], 0.f);
  }
  __syncthreads();
  // FC1: 8 nodes x 64 oz. thread: (oz = tid&63, grp = tid>>6) -> nodes 2*grp, 2*grp+1.
  {
    int oz = tid & 63;
    int grp = tid >> 6;
    int n0 = grp * 2, n1 = n0 + 1;
    float z0 = fb1[oz], z1 = z0;
    for (int c = 0; c < HID2; c++) {
      float f = F1[c * 64 + oz];
      z0 += lastv[n0 * 128 + c] * f;
      z1 += lastv[n1 * 128 + c] * f;
    }
    zs[n0 * 64 + oz] = fmaxf(z0, 0.f);
    zs[n1 * 64 + oz] = fmaxf(z1, 0.f);
  }
  __syncthreads();
  // FC2 + softplus
  if (tid < 96) {
    int node = tid / 12;
    int oo = tid - node * 12;
    float p = fb2[oo];
    const float* Z = zs + node * 64;
    for (int c = 0; c < 64; c++) p += Z[c] * F2[c * 12 + oo];
    float sp = fmaxf(p, 0.f) + log1pf(expf(-fabsf(p)));
    out[(size_t)(nb + node) * 12 + oo] = sp;
  }
}

// ---------------- launch ----------------

extern "C" void kernel_launch(void* const* d_in, const int* in_sizes, int n_in,
                              void* d_out, int out_size, void* d_ws, size_t ws_size,
                              hipStream_t stream) {
  const float* x = (const float*)d_in[0];
  const int* edge = (const int*)d_in[1];
  const float* W1 = (const float*)d_in[2];
  const float* b1 = (const float*)d_in[3];
  const float* K1 = (const float*)d_in[4];
  const float* kb1 = (const float*)d_in[5];
  const float* W2 = (const float*)d_in[6];
  const float* b2 = (const float*)d_in[7];
  const float* K2 = (const float*)d_in[8];
  const float* kb2 = (const float*)d_in[9];
  const float* F1 = (const float*)d_in[10];
  const float* fb1 = (const float*)d_in[11];
  const float* F2 = (const float*)d_in[12];
  const float* fb2 = (const float*)d_in[13];
  float* out = (float*)d_out;

  char* ws = (char*)d_ws;
  size_t p = 0;
  auto alloc = [&](size_t bytes) -> char* {
    char* r = ws + p;
    p = (p + bytes + 255) & ~(size_t)255;
    return r;
  };
  float* T1 = (float*)alloc(N_NODES * 2 * 64 * 4);   // (N,2,64)
  float* A2 = (float*)alloc(N_NODES * 2 * 64 * 4);   // (N,2,64)
  int* counts = (int*)alloc(N_NODES * 4);
  int* offsets = (int*)alloc((N_NODES + 1) * 4);
  int* cursor = (int*)alloc(N_NODES * 4);
  float* dinv = (float*)alloc(N_NODES * 4);
  int* csr_src = (int*)alloc(N_EDGES * 4);
  float* csr_norm = (float*)alloc(N_EDGES * 4);
  float* Kt1 = (float*)alloc(HID * HID * 3 * 4);
  float* Kt2 = (float*)alloc(HID2 * HID2 * 3 * 4);
  (void)ws_size;
  (void)in_sizes;
  (void)n_in;
  (void)out_size;

  const int* src = edge;
  const int* dst = edge + N_EDGES;

  hipMemsetAsync(counts, 0, N_NODES * 4, stream);
  hist_kernel<<<(N_EDGES + 255) / 256, 256, 0, stream>>>(dst, counts);
  scan_kernel<<<1, 1024, 0, stream>>>(counts, offsets, cursor, dinv);
  scatter_ktt_kernel<<<865, 256, 0, stream>>>(src, dst, dinv, cursor, csr_src, csr_norm, K1, Kt1,
                                              K2, Kt2);
  layer1_kernel<<<625, 256, 0, stream>>>(x, csr_src, csr_norm, offsets, dinv, W1, b1, Kt1, kb1,
                                         T1);
  agg2_kernel<<<N_NODES / 8, 256, 0, stream>>>(T1, csr_src, csr_norm, offsets, dinv, A2);
  layer2_kernel<<<N_NODES / 8, 256, 0, stream>>>(A2, W2, b2, Kt2, kb2, F1, fb1, F2, fb2, out);
}

// Round 12
// 192.041 us; speedup vs baseline: 4.7105x; 1.0760x over previous
//
#include <hip/hip_runtime.h>
#include <math.h>

#define N_NODES 10000
#define N_EDGES 160000
#define SEQ 16
#define HID 64
#define HID2 128

// DCE: only out[:, -1, :] of tconv2 feeds the head => compute
//   layer1 (agg4/linw1) at t=13,14,15 ; tconv1 at t=14,15 ;
//   layer2 (agg2/lin2)  at t=14,15    ; tconv2 at t=15 (fused with FC head).
// 6 dispatches: memset, hist, scan, scatter+ktT, layer1, layer2 (agg2 fused in).

// ---------------- graph preprocessing ----------------

__global__ __launch_bounds__(256) void hist_kernel(const int* __restrict__ dst,
                                                   int* __restrict__ counts) {
  int e = blockIdx.x * 256 + threadIdx.x;
  if (e < N_EDGES) atomicAdd(&counts[dst[e]], 1);
}

__global__ __launch_bounds__(1024) void scan_kernel(const int* __restrict__ counts,
                                                    int* __restrict__ offsets,
                                                    int* __restrict__ cursor,
                                                    float* __restrict__ dinv) {
  __shared__ int partial[1024];
  const int CHUNK = 10;  // 1024*10 = 10240 >= 10000
  int tid = threadIdx.x;
  int base = tid * CHUNK;
  int s = 0;
  for (int k = 0; k < CHUNK; k++) {
    int idx = base + k;
    if (idx < N_NODES) s += counts[idx];
  }
  partial[tid] = s;
  __syncthreads();
  for (int d = 1; d < 1024; d <<= 1) {
    int t = (tid >= d) ? partial[tid - d] : 0;
    __syncthreads();
    partial[tid] += t;
    __syncthreads();
  }
  int run = (tid == 0) ? 0 : partial[tid - 1];
  for (int k = 0; k < CHUNK; k++) {
    int idx = base + k;
    if (idx < N_NODES) {
      offsets[idx] = run;
      cursor[idx] = run;
      dinv[idx] = rsqrtf((float)counts[idx] + 1.0f);
      run += counts[idx];
    }
  }
  if (tid == 1023) offsets[N_NODES] = partial[1023];
}

// fused: blocks 0..624 scatter edges; 625..672 transpose K1; 673..864 transpose K2.
__global__ __launch_bounds__(256) void scatter_ktt_kernel(
    const int* __restrict__ src, const int* __restrict__ dst, const float* __restrict__ dinv,
    int* __restrict__ cursor, int* __restrict__ csr_src, float* __restrict__ csr_norm,
    const float* __restrict__ K1, float* __restrict__ Kt1, const float* __restrict__ K2,
    float* __restrict__ Kt2) {
  int b = blockIdx.x;
  int tid = threadIdx.x;
  if (b < 625) {
    int e = b * 256 + tid;  // 625*256 == 160000 exactly
    int d = dst[e];
    int s = src[e];
    int pos = atomicAdd(&cursor[d], 1);
    csr_src[pos] = s;
    csr_norm[pos] = dinv[s] * dinv[d];
  } else if (b < 673) {
    int idx = (b - 625) * 256 + tid;  // 48*256 == 12288 == 64*64*3 exactly
    int w = idx % 3;
    int i = (idx / 3) % HID;
    int o = idx / (3 * HID);
    Kt1[(i * 3 + w) * HID + o] = K1[idx];
  } else {
    int idx = (b - 673) * 256 + tid;  // 192*256 == 49152 == 128*128*3 exactly
    int w = idx % 3;
    int i = (idx / 3) % HID2;
    int o = idx / (3 * HID2);
    Kt2[(i * 3 + w) * HID2 + o] = K2[idx];
  }
}

// ---------------- layer 1 fused: agg4(t=13..15) -> @W1+b1,relu -> tconv1(t=14,15) ----------------
// 16 nodes/block, 625 blocks.

__global__ __launch_bounds__(256) void layer1_kernel(
    const float* __restrict__ x, const int* __restrict__ csr_src,
    const float* __restrict__ csr_norm, const int* __restrict__ offsets,
    const float* __restrict__ dinv, const float* __restrict__ W1, const float* __restrict__ b1,
    const float* __restrict__ Kt1, const float* __restrict__ kb1, float* __restrict__ T1) {
  __shared__ float aggXs[48 * 4];  // [row = n_local*3 + t'][4]
  __shared__ float H1s[16 * 192];  // [n_local][t'*64 + o]
  int tid = threadIdx.x;
  int nb = blockIdx.x * 16;
  // phase A: gather-agg, 48 rows (n_local, t), 4 edge-lanes per row (192 threads).
  if (tid < 192) {
    int row = tid >> 2;   // 0..47
    int lane = tid & 3;   // edge lane
    int n = nb + row / 3;
    int t = 13 + row % 3;
    int beg = offsets[n], end = offsets[n + 1];
    float4 acc = make_float4(0.f, 0.f, 0.f, 0.f);
    for (int e = beg + lane; e < end; e += 4) {
      int s = csr_src[e];
      float w = csr_norm[e];
      float4 xv = *(const float4*)(x + (size_t)s * 64 + t * 4);
      acc.x += xv.x * w;
      acc.y += xv.y * w;
      acc.z += xv.z * w;
      acc.w += xv.w * w;
    }
    if (lane == 0) {  // self term once
      float w = dinv[n];
      w = w * w;
      float4 xv = *(const float4*)(x + (size_t)n * 64 + t * 4);
      acc.x += xv.x * w;
      acc.y += xv.y * w;
      acc.z += xv.z * w;
      acc.w += xv.w * w;
    }
    // 4-lane tree reduce (groups aligned within a 64-lane wave)
#pragma unroll
    for (int m = 1; m <= 2; m <<= 1) {
      acc.x += __shfl_xor(acc.x, m);
      acc.y += __shfl_xor(acc.y, m);
      acc.z += __shfl_xor(acc.z, m);
      acc.w += __shfl_xor(acc.w, m);
    }
    if (lane == 0) *(float4*)(aggXs + row * 4) = acc;
  }
  __syncthreads();
  // phase B: linw1 — 48 rows x 64 o = 3072 outputs, 12 per thread.
  // note row*64 == (row/3)*192 + (row%3)*64, so H1s[row*64+o] is [n_local][t'][o].
#pragma unroll
  for (int k = 0; k < 12; k++) {
    int idx = tid + k * 256;
    int row = idx >> 6;
    int o = idx & 63;
    const float* a = aggXs + row * 4;
    float acc = b1[o] + a[0] * W1[o] + a[1] * W1[64 + o] + a[2] * W1[128 + o] + a[3] * W1[192 + o];
    H1s[row * 64 + o] = fmaxf(acc, 0.f);
  }
  __syncthreads();
  // phase C: tconv1 at t=14,15. thread: (g = tid>>7, rem = tt*64+o); 8 nodes per thread
  // (nodes g, g+2, ..., g+14) so each Kt1 load feeds 8 FMAs.
  {
    int g = tid >> 7;
    int rem = tid & 127;
    int tt = rem >> 6;  // wave-uniform
    int o = rem & 63;
    float acc[8];
    float kbv = kb1[o];
#pragma unroll
    for (int j = 0; j < 8; j++) acc[j] = kbv;
    if (tt == 0) {  // out t=14: rows 0,1,2 with w=0,1,2
      for (int i = 0; i < 64; i++) {
        float k0 = Kt1[(i * 3 + 0) * 64 + o];
        float k1 = Kt1[(i * 3 + 1) * 64 + o];
        float k2 = Kt1[(i * 3 + 2) * 64 + o];
#pragma unroll
        for (int j = 0; j < 8; j++) {
          const float* L = H1s + (g + 2 * j) * 192;
          acc[j] += L[i] * k0 + L[64 + i] * k1 + L[128 + i] * k2;
        }
      }
    } else {  // out t=15: rows 1,2 with w=0,1 (w=2 hits pad)
      for (int i = 0; i < 64; i++) {
        float k0 = Kt1[(i * 3 + 0) * 64 + o];
        float k1 = Kt1[(i * 3 + 1) * 64 + o];
#pragma unroll
        for (int j = 0; j < 8; j++) {
          const float* L = H1s + (g + 2 * j) * 192;
          acc[j] += L[64 + i] * k0 + L[128 + i] * k1;
        }
      }
    }
#pragma unroll
    for (int j = 0; j < 8; j++) {
      T1[(size_t)(nb + g + 2 * j) * 128 + rem] = fmaxf(acc[j], 0.f);
    }
  }
}

// ---------------- layer 2 fused: agg2 -> lin2 -> tconv2(t=15) -> FC head -> softplus -------------
// 8 nodes/block, 1250 blocks. agg2 gathers T1 over each node's edges directly into LDS.

__global__ __launch_bounds__(256) void layer2_kernel(
    const float* __restrict__ T1, const int* __restrict__ csr_src,
    const float* __restrict__ csr_norm, const int* __restrict__ offsets,
    const float* __restrict__ dinv, const float* __restrict__ W2, const float* __restrict__ b2,
    const float* __restrict__ Kt2, const float* __restrict__ kb2, const float* __restrict__ F1,
    const float* __restrict__ fb1, const float* __restrict__ F2, const float* __restrict__ fb2,
    float* __restrict__ out) {
  __shared__ float A2s[8 * 128];    // [n_local][tt*64 + c]
  __shared__ float H2s[8 * 256];    // [n_local][tt*128 + o]
  __shared__ float lastv[8 * 128];  // relu(tconv2 t=15)
  __shared__ float zs[8 * 64];
  int tid = threadIdx.x;
  int nb = blockIdx.x * 8;
  // phase agg2: 32 threads per node, one float4 slice each.
  {
    int n = nb + (tid >> 5);
    int v = tid & 31;
    int beg = offsets[n], end = offsets[n + 1];
    float4 acc = make_float4(0.f, 0.f, 0.f, 0.f);
    for (int e = beg; e < end; ++e) {
      int s = csr_src[e];
      float w = csr_norm[e];
      float4 tv = ((const float4*)(T1 + (size_t)s * 128))[v];
      acc.x += tv.x * w;
      acc.y += tv.y * w;
      acc.z += tv.z * w;
      acc.w += tv.w * w;
    }
    {
      float w = dinv[n];
      w = w * w;
      float4 tv = ((const float4*)(T1 + (size_t)n * 128))[v];
      acc.x += tv.x * w;
      acc.y += tv.y * w;
      acc.z += tv.z * w;
      acc.w += tv.w * w;
    }
    *(float4*)(A2s + (tid >> 5) * 128 + v * 4) = acc;
  }
  __syncthreads();
  // lin2: 16 (n,tt) pairs x 128 o. thread: (o = tid&127, g = tid>>7), pairs g, g+2, ..., g+14.
  {
    int o = tid & 127;
    int g = tid >> 7;
    float acc[8];
    float bv = b2[o];
#pragma unroll
    for (int j = 0; j < 8; j++) acc[j] = bv;
    for (int c = 0; c < 64; c++) {
      float w = W2[c * 128 + o];
#pragma unroll
      for (int j = 0; j < 8; j++) {
        int p = g + 2 * j;  // pair: n_local = p>>1, tt = p&1
        acc[j] += A2s[(p >> 1) * 128 + (p & 1) * 64 + c] * w;
      }
    }
#pragma unroll
    for (int j = 0; j < 8; j++) {
      int p = g + 2 * j;
      H2s[(p >> 1) * 256 + (p & 1) * 128 + o] = fmaxf(acc[j], 0.f);
    }
  }
  __syncthreads();
  // tconv2 t=15: w=0 -> t=14 (row 0), w=1 -> t=15 (row 1), w=2 -> pad.
  {
    int half = tid >> 7;
    int o = tid & 127;
    float acc[4];
    float kbv = kb2[o];
#pragma unroll
    for (int k = 0; k < 4; k++) acc[k] = kbv;
    for (int i = 0; i < 128; i++) {
      float k0 = Kt2[(i * 3 + 0) * 128 + o];
      float k1 = Kt2[(i * 3 + 1) * 128 + o];
#pragma unroll
      for (int k = 0; k < 4; k++) {
        const float* L = H2s + (half + 2 * k) * 256;
        acc[k] += L[i] * k0 + L[128 + i] * k1;
      }
    }
#pragma unroll
    for (int k = 0; k < 4; k++) lastv[(half + 2 * k) * 128 + o] = fmaxf(acc[k], 0.f);
  }
  __syncthreads();
  // FC1: 8 nodes x 64 oz. thread: (oz = tid&63, grp = tid>>6) -> nodes 2*grp, 2*grp+1.
  {
    int oz = tid & 63;
    int grp = tid >> 6;
    int n0 = grp * 2, n1 = n0 + 1;
    float z0 = fb1[oz], z1 = z0;
    for (int c = 0; c < HID2; c++) {
      float f = F1[c * 64 + oz];
      z0 += lastv[n0 * 128 + c] * f;
      z1 += lastv[n1 * 128 + c] * f;
    }
    zs[n0 * 64 + oz] = fmaxf(z0, 0.f);
    zs[n1 * 64 + oz] = fmaxf(z1, 0.f);
  }
  __syncthreads();
  // FC2 + softplus
  if (tid < 96) {
    int node = tid / 12;
    int oo = tid - node * 12;
    float p = fb2[oo];
    const float* Z = zs + node * 64;
    for (int c = 0; c < 64; c++) p += Z[c] * F2[c * 12 + oo];
    float sp = fmaxf(p, 0.f) + log1pf(expf(-fabsf(p)));
    out[(size_t)(nb + node) * 12 + oo] = sp;
  }
}

// ---------------- launch ----------------

extern "C" void kernel_launch(void* const* d_in, const int* in_sizes, int n_in,
                              void* d_out, int out_size, void* d_ws, size_t ws_size,
                              hipStream_t stream) {
  const float* x = (const float*)d_in[0];
  const int* edge = (const int*)d_in[1];
  const float* W1 = (const float*)d_in[2];
  const float* b1 = (const float*)d_in[3];
  const float* K1 = (const float*)d_in[4];
  const float* kb1 = (const float*)d_in[5];
  const float* W2 = (const float*)d_in[6];
  const float* b2 = (const float*)d_in[7];
  const float* K2 = (const float*)d_in[8];
  const float* kb2 = (const float*)d_in[9];
  const float* F1 = (const float*)d_in[10];
  const float* fb1 = (const float*)d_in[11];
  const float* F2 = (const float*)d_in[12];
  const float* fb2 = (const float*)d_in[13];
  float* out = (float*)d_out;

  char* ws = (char*)d_ws;
  size_t p = 0;
  auto alloc = [&](size_t bytes) -> char* {
    char* r = ws + p;
    p = (p + bytes + 255) & ~(size_t)255;
    return r;
  };
  float* T1 = (float*)alloc(N_NODES * 2 * 64 * 4);  // (N,2,64)
  int* counts = (int*)alloc(N_NODES * 4);
  int* offsets = (int*)alloc((N_NODES + 1) * 4);
  int* cursor = (int*)alloc(N_NODES * 4);
  float* dinv = (float*)alloc(N_NODES * 4);
  int* csr_src = (int*)alloc(N_EDGES * 4);
  float* csr_norm = (float*)alloc(N_EDGES * 4);
  float* Kt1 = (float*)alloc(HID * HID * 3 * 4);
  float* Kt2 = (float*)alloc(HID2 * HID2 * 3 * 4);
  (void)ws_size;
  (void)in_sizes;
  (void)n_in;
  (void)out_size;

  const int* src = edge;
  const int* dst = edge + N_EDGES;

  hipMemsetAsync(counts, 0, N_NODES * 4, stream);
  hist_kernel<<<(N_EDGES + 255) / 256, 256, 0, stream>>>(dst, counts);
  scan_kernel<<<1, 1024, 0, stream>>>(counts, offsets, cursor, dinv);
  scatter_ktt_kernel<<<865, 256, 0, stream>>>(src, dst, dinv, cursor, csr_src, csr_norm, K1, Kt1,
                                              K2, Kt2);
  layer1_kernel<<<625, 256, 0, stream>>>(x, csr_src, csr_norm, offsets, dinv, W1, b1, Kt1, kb1,
                                         T1);
  layer2_kernel<<<N_NODES / 8, 256, 0, stream>>>(T1, csr_src, csr_norm, offsets, dinv, W2, b2,
                                                 Kt2, kb2, F1, fb1, F2, fb2, out);
}

// Round 16
// 187.613 us; speedup vs baseline: 4.8216x; 1.0236x over previous
//
#include <hip/hip_runtime.h>
#include <math.h>

#define N_NODES 10000
#define N_EDGES 160000
#define SEQ 16
#define HID 64
#define HID2 128

// DCE: only out[:, -1, :] of tconv2 feeds the head => compute
//   layer1 (agg4/linw1) at t=13,14,15 ; tconv1 at t=14,15 ;
//   layer2 (agg2/lin2)  at t=14,15    ; tconv2 at t=15 (fused with FC head).
// 6 dispatches: memset, hist, scan, scatter+ktT, layer1, layer2 (agg2 fused in).

// ---------------- graph preprocessing ----------------

__global__ __launch_bounds__(256) void hist_kernel(const int* __restrict__ dst,
                                                   int* __restrict__ counts) {
  int e = blockIdx.x * 256 + threadIdx.x;
  if (e < N_EDGES) atomicAdd(&counts[dst[e]], 1);
}

__global__ __launch_bounds__(1024) void scan_kernel(const int* __restrict__ counts,
                                                    int* __restrict__ offsets,
                                                    int* __restrict__ cursor,
                                                    float* __restrict__ dinv) {
  __shared__ int partial[1024];
  const int CHUNK = 10;  // 1024*10 = 10240 >= 10000
  int tid = threadIdx.x;
  int base = tid * CHUNK;
  int s = 0;
  for (int k = 0; k < CHUNK; k++) {
    int idx = base + k;
    if (idx < N_NODES) s += counts[idx];
  }
  partial[tid] = s;
  __syncthreads();
  for (int d = 1; d < 1024; d <<= 1) {
    int t = (tid >= d) ? partial[tid - d] : 0;
    __syncthreads();
    partial[tid] += t;
    __syncthreads();
  }
  int run = (tid == 0) ? 0 : partial[tid - 1];
  for (int k = 0; k < CHUNK; k++) {
    int idx = base + k;
    if (idx < N_NODES) {
      offsets[idx] = run;
      cursor[idx] = run;
      dinv[idx] = rsqrtf((float)counts[idx] + 1.0f);
      run += counts[idx];
    }
  }
  if (tid == 1023) offsets[N_NODES] = partial[1023];
}

// fused: blocks 0..624 scatter edges; 625..672 transpose K1; 673..864 transpose K2.
__global__ __launch_bounds__(256) void scatter_ktt_kernel(
    const int* __restrict__ src, const int* __restrict__ dst, const float* __restrict__ dinv,
    int* __restrict__ cursor, int* __restrict__ csr_src, float* __restrict__ csr_norm,
    const float* __restrict__ K1, float* __restrict__ Kt1, const float* __restrict__ K2,
    float* __restrict__ Kt2) {
  int b = blockIdx.x;
  int tid = threadIdx.x;
  if (b < 625) {
    int e = b * 256 + tid;  // 625*256 == 160000 exactly
    int d = dst[e];
    int s = src[e];
    int pos = atomicAdd(&cursor[d], 1);
    csr_src[pos] = s;
    csr_norm[pos] = dinv[s] * dinv[d];
  } else if (b < 673) {
    int idx = (b - 625) * 256 + tid;  // 48*256 == 12288 == 64*64*3 exactly
    int w = idx % 3;
    int i = (idx / 3) % HID;
    int o = idx / (3 * HID);
    Kt1[(i * 3 + w) * HID + o] = K1[idx];
  } else {
    int idx = (b - 673) * 256 + tid;  // 192*256 == 49152 == 128*128*3 exactly
    int w = idx % 3;
    int i = (idx / 3) % HID2;
    int o = idx / (3 * HID2);
    Kt2[(i * 3 + w) * HID2 + o] = K2[idx];
  }
}

// ---------------- layer 1 fused: agg4(t=13..15) -> @W1+b1,relu -> tconv1(t=14,15) ----------------
// 16 nodes/block, 625 blocks. (unchanged from validated R12 state)

__global__ __launch_bounds__(256) void layer1_kernel(
    const float* __restrict__ x, const int* __restrict__ csr_src,
    const float* __restrict__ csr_norm, const int* __restrict__ offsets,
    const float* __restrict__ dinv, const float* __restrict__ W1, const float* __restrict__ b1,
    const float* __restrict__ Kt1, const float* __restrict__ kb1, float* __restrict__ T1) {
  __shared__ float aggXs[48 * 4];  // [row = n_local*3 + t'][4]
  __shared__ float H1s[16 * 192];  // [n_local][t'*64 + o]
  int tid = threadIdx.x;
  int nb = blockIdx.x * 16;
  // phase A: gather-agg, 48 rows (n_local, t), 4 edge-lanes per row (192 threads).
  if (tid < 192) {
    int row = tid >> 2;  // 0..47
    int lane = tid & 3;  // edge lane
    int n = nb + row / 3;
    int t = 13 + row % 3;
    int beg = offsets[n], end = offsets[n + 1];
    float4 acc = make_float4(0.f, 0.f, 0.f, 0.f);
    for (int e = beg + lane; e < end; e += 4) {
      int s = csr_src[e];
      float w = csr_norm[e];
      float4 xv = *(const float4*)(x + (size_t)s * 64 + t * 4);
      acc.x += xv.x * w;
      acc.y += xv.y * w;
      acc.z += xv.z * w;
      acc.w += xv.w * w;
    }
    if (lane == 0) {  // self term once
      float w = dinv[n];
      w = w * w;
      float4 xv = *(const float4*)(x + (size_t)n * 64 + t * 4);
      acc.x += xv.x * w;
      acc.y += xv.y * w;
      acc.z += xv.z * w;
      acc.w += xv.w * w;
    }
    // 4-lane tree reduce (groups aligned within a 64-lane wave)
#pragma unroll
    for (int m = 1; m <= 2; m <<= 1) {
      acc.x += __shfl_xor(acc.x, m);
      acc.y += __shfl_xor(acc.y, m);
      acc.z += __shfl_xor(acc.z, m);
      acc.w += __shfl_xor(acc.w, m);
    }
    if (lane == 0) *(float4*)(aggXs + row * 4) = acc;
  }
  __syncthreads();
  // phase B: linw1 — 48 rows x 64 o = 3072 outputs, 12 per thread.
#pragma unroll
  for (int k = 0; k < 12; k++) {
    int idx = tid + k * 256;
    int row = idx >> 6;
    int o = idx & 63;
    const float* a = aggXs + row * 4;
    float acc = b1[o] + a[0] * W1[o] + a[1] * W1[64 + o] + a[2] * W1[128 + o] + a[3] * W1[192 + o];
    H1s[row * 64 + o] = fmaxf(acc, 0.f);
  }
  __syncthreads();
  // phase C: tconv1 at t=14,15. 8 nodes per thread so each Kt1 load feeds 8 FMAs.
  {
    int g = tid >> 7;
    int rem = tid & 127;
    int tt = rem >> 6;  // wave-uniform
    int o = rem & 63;
    float acc[8];
    float kbv = kb1[o];
#pragma unroll
    for (int j = 0; j < 8; j++) acc[j] = kbv;
    if (tt == 0) {  // out t=14: rows 0,1,2 with w=0,1,2
      for (int i = 0; i < 64; i++) {
        float k0 = Kt1[(i * 3 + 0) * 64 + o];
        float k1 = Kt1[(i * 3 + 1) * 64 + o];
        float k2 = Kt1[(i * 3 + 2) * 64 + o];
#pragma unroll
        for (int j = 0; j < 8; j++) {
          const float* L = H1s + (g + 2 * j) * 192;
          acc[j] += L[i] * k0 + L[64 + i] * k1 + L[128 + i] * k2;
        }
      }
    } else {  // out t=15: rows 1,2 with w=0,1 (w=2 hits pad)
      for (int i = 0; i < 64; i++) {
        float k0 = Kt1[(i * 3 + 0) * 64 + o];
        float k1 = Kt1[(i * 3 + 1) * 64 + o];
#pragma unroll
        for (int j = 0; j < 8; j++) {
          const float* L = H1s + (g + 2 * j) * 192;
          acc[j] += L[64 + i] * k0 + L[128 + i] * k1;
        }
      }
    }
#pragma unroll
    for (int j = 0; j < 8; j++) {
      T1[(size_t)(nb + g + 2 * j) * 128 + rem] = fmaxf(acc[j], 0.f);
    }
  }
}

// ---------------- layer 2 fused: agg2 -> lin2 -> tconv2(t=15) -> FC head -> softplus -------------
// 8 nodes/block, 1250 blocks. Gather change vs R12: block's CSR slice staged to LDS first
// (coalesced), so per-edge loop has a single global-latency level (T1) and pipelines.

#define CHUNK_E 1024

__global__ __launch_bounds__(256) void layer2_kernel(
    const float* __restrict__ T1, const int* __restrict__ csr_src,
    const float* __restrict__ csr_norm, const int* __restrict__ offsets,
    const float* __restrict__ dinv, const float* __restrict__ W2, const float* __restrict__ b2,
    const float* __restrict__ Kt2, const float* __restrict__ kb2, const float* __restrict__ F1,
    const float* __restrict__ fb1, const float* __restrict__ F2, const float* __restrict__ fb2,
    float* __restrict__ out) {
  __shared__ float A2s[8 * 128];    // [n_local][tt*64 + c]
  __shared__ float H2s[8 * 256];    // [n_local][tt*128 + o]
  __shared__ float lastv[8 * 128];  // relu(tconv2 t=15)
  __shared__ float zs[8 * 64];
  __shared__ int ls_src[CHUNK_E];
  __shared__ float ls_w[CHUNK_E];
  int tid = threadIdx.x;
  int nb = blockIdx.x * 8;
  // phase agg2: stage block's contiguous edge slice to LDS, then 32 threads/node gather T1.
  {
    int blk_beg = offsets[nb];
    int blk_tot = offsets[nb + 8] - blk_beg;
    int n = nb + (tid >> 5);
    int v = tid & 31;
    int beg = offsets[n] - blk_beg, end = offsets[n + 1] - blk_beg;  // relative
    float4 acc = make_float4(0.f, 0.f, 0.f, 0.f);
    for (int c0 = 0; c0 < blk_tot; c0 += CHUNK_E) {
      int cnt = min(blk_tot - c0, CHUNK_E);
      __syncthreads();  // protect buffer reuse (no-op cost on first pass)
      for (int j = tid; j < cnt; j += 256) {
        ls_src[j] = csr_src[blk_beg + c0 + j];
        ls_w[j] = csr_norm[blk_beg + c0 + j];
      }
      __syncthreads();
      int e0 = max(beg, c0), e1 = min(end, c0 + cnt);
#pragma unroll 4
      for (int e = e0; e < e1; ++e) {
        int s = ls_src[e - c0];
        float w = ls_w[e - c0];
        float4 tv = ((const float4*)(T1 + (size_t)s * 128))[v];
        acc.x += tv.x * w;
        acc.y += tv.y * w;
        acc.z += tv.z * w;
        acc.w += tv.w * w;
      }
    }
    {  // self term
      float w = dinv[n];
      w = w * w;
      float4 tv = ((const float4*)(T1 + (size_t)n * 128))[v];
      acc.x += tv.x * w;
      acc.y += tv.y * w;
      acc.z += tv.z * w;
      acc.w += tv.w * w;
    }
    *(float4*)(A2s + (tid >> 5) * 128 + v * 4) = acc;
  }
  __syncthreads();
  // lin2: 16 (n,tt) pairs x 128 o. thread: (o = tid&127, g = tid>>7), pairs g, g+2, ..., g+14.
  {
    int o = tid & 127;
    int g = tid >> 7;
    float acc[8];
    float bv = b2[o];
#pragma unroll
    for (int j = 0; j < 8; j++) acc[j] = bv;
    for (int c = 0; c < 64; c++) {
      float w = W2[c * 128 + o];
#pragma unroll
      for (int j = 0; j < 8; j++) {
        int p = g + 2 * j;  // pair: n_local = p>>1, tt = p&1
        acc[j] += A2s[(p >> 1) * 128 + (p & 1) * 64 + c] * w;
      }
    }
#pragma unroll
    for (int j = 0; j < 8; j++) {
      int p = g + 2 * j;
      H2s[(p >> 1) * 256 + (p & 1) * 128 + o] = fmaxf(acc[j], 0.f);
    }
  }
  __syncthreads();
  // tconv2 t=15: w=0 -> t=14 (row 0), w=1 -> t=15 (row 1), w=2 -> pad.
  {
    int half = tid >> 7;
    int o = tid & 127;
    float acc[4];
    float kbv = kb2[o];
#pragma unroll
    for (int k = 0; k < 4; k++) acc[k] = kbv;
    for (int i = 0; i < 128; i++) {
      float k0 = Kt2[(i * 3 + 0) * 128 + o];
      float k1 = Kt2[(i * 3 + 1) * 128 + o];
#pragma unroll
      for (int k = 0; k < 4; k++) {
        const float* L = H2s + (half + 2 * k) * 256;
        acc[k] += L[i] * k0 + L[128 + i] * k1;
      }
    }
#pragma unroll
    for (int k = 0; k < 4; k++) lastv[(half + 2 * k) * 128 + o] = fmaxf(acc[k], 0.f);
  }
  __syncthreads();
  // FC1: 8 nodes x 64 oz. thread: (oz = tid&63, grp = tid>>6) -> nodes 2*grp, 2*grp+1.
  {
    int oz = tid & 63;
    int grp = tid >> 6;
    int n0 = grp * 2, n1 = n0 + 1;
    float z0 = fb1[oz], z1 = z0;
    for (int c = 0; c < HID2; c++) {
      float f = F1[c * 64 + oz];
      z0 += lastv[n0 * 128 + c] * f;
      z1 += lastv[n1 * 128 + c] * f;
    }
    zs[n0 * 64 + oz] = fmaxf(z0, 0.f);
    zs[n1 * 64 + oz] = fmaxf(z1, 0.f);
  }
  __syncthreads();
  // FC2 + softplus
  if (tid < 96) {
    int node = tid / 12;
    int oo = tid - node * 12;
    float p = fb2[oo];
    const float* Z = zs + node * 64;
    for (int c = 0; c < 64; c++) p += Z[c] * F2[c * 12 + oo];
    float sp = fmaxf(p, 0.f) + log1pf(expf(-fabsf(p)));
    out[(size_t)(nb + node) * 12 + oo] = sp;
  }
}

// ---------------- launch ----------------

extern "C" void kernel_launch(void* const* d_in, const int* in_sizes, int n_in,
                              void* d_out, int out_size, void* d_ws, size_t ws_size,
                              hipStream_t stream) {
  const float* x = (const float*)d_in[0];
  const int* edge = (const int*)d_in[1];
  const float* W1 = (const float*)d_in[2];
  const float* b1 = (const float*)d_in[3];
  const float* K1 = (const float*)d_in[4];
  const float* kb1 = (const float*)d_in[5];
  const float* W2 = (const float*)d_in[6];
  const float* b2 = (const float*)d_in[7];
  const float* K2 = (const float*)d_in[8];
  const float* kb2 = (const float*)d_in[9];
  const float* F1 = (const float*)d_in[10];
  const float* fb1 = (const float*)d_in[11];
  const float* F2 = (const float*)d_in[12];
  const float* fb2 = (const float*)d_in[13];
  float* out = (float*)d_out;

  char* ws = (char*)d_ws;
  size_t p = 0;
  auto alloc = [&](size_t bytes) -> char* {
    char* r = ws + p;
    p = (p + bytes + 255) & ~(size_t)255;
    return r;
  };
  float* T1 = (float*)alloc(N_NODES * 2 * 64 * 4);  // (N,2,64)
  int* counts = (int*)alloc(N_NODES * 4);
  int* offsets = (int*)alloc((N_NODES + 1) * 4);
  int* cursor = (int*)alloc(N_NODES * 4);
  float* dinv = (float*)alloc(N_NODES * 4);
  int* csr_src = (int*)alloc(N_EDGES * 4);
  float* csr_norm = (float*)alloc(N_EDGES * 4);
  float* Kt1 = (float*)alloc(HID * HID * 3 * 4);
  float* Kt2 = (float*)alloc(HID2 * HID2 * 3 * 4);
  (void)ws_size;
  (void)in_sizes;
  (void)n_in;
  (void)out_size;

  const int* src = edge;
  const int* dst = edge + N_EDGES;

  hipMemsetAsync(counts, 0, N_NODES * 4, stream);
  hist_kernel<<<(N_EDGES + 255) / 256, 256, 0, stream>>>(dst, counts);
  scan_kernel<<<1, 1024, 0, stream>>>(counts, offsets, cursor, dinv);
  scatter_ktt_kernel<<<865, 256, 0, stream>>>(src, dst, dinv, cursor, csr_src, csr_norm, K1, Kt1,
                                              K2, Kt2);
  layer1_kernel<<<625, 256, 0, stream>>>(x, csr_src, csr_norm, offsets, dinv, W1, b1, Kt1, kb1,
                                         T1);
  layer2_kernel<<<N_NODES / 8, 256, 0, stream>>>(T1, csr_src, csr_norm, offsets, dinv, W2, b2,
                                                 Kt2, kb2, F1, fb1, F2, fb2, out);
}